// Round 4
// baseline (771.094 us; speedup 1.0000x reference)
//
#include <hip/hip_runtime.h>

typedef float f4v __attribute__((ext_vector_type(4)));
typedef short s8v __attribute__((ext_vector_type(8)));

__device__ __forceinline__ unsigned short f2bf(float x){
  union { float f; unsigned u; } v; v.f = x;
  unsigned r = v.u + 0x7fffu + ((v.u >> 16) & 1u);
  return (unsigned short)(r >> 16);
}
__device__ __forceinline__ float bf2f(unsigned short b){
  union { unsigned u; float f; } v; v.u = ((unsigned)b) << 16;
  return v.f;
}
__device__ __forceinline__ void split8(const float* __restrict__ p, s8v& h, s8v& l){
  float4 v0 = *reinterpret_cast<const float4*>(p);
  float4 v1 = *reinterpret_cast<const float4*>(p + 4);
  float a[8] = {v0.x, v0.y, v0.z, v0.w, v1.x, v1.y, v1.z, v1.w};
#pragma unroll
  for (int j = 0; j < 8; ++j) {
    unsigned short hi = f2bf(a[j]);
    h[j] = (short)hi;
    l[j] = (short)f2bf(a[j] - bf2f(hi));
  }
}
__device__ __forceinline__ void zero8(s8v& v){
#pragma unroll
  for (int j = 0; j < 8; ++j) v[j] = 0;
}

// Grid barrier. RELAXED polls (no per-iteration cache invalidate!) +
// one release fence before arrival, one acquire fence after exit.
__device__ __forceinline__ void gbar(unsigned* ctr, unsigned nb){
  __syncthreads();
  if (threadIdx.x == 0) {
    __threadfence();   // release: L2 writeback
    __hip_atomic_fetch_add(ctr, 1u, __ATOMIC_RELAXED, __HIP_MEMORY_SCOPE_AGENT);
    while (__hip_atomic_load(ctr, __ATOMIC_RELAXED, __HIP_MEMORY_SCOPE_AGENT) < nb)
      __builtin_amdgcn_s_sleep(8);
    __threadfence();   // acquire: invalidate once
  }
  __syncthreads();
}

// ---------------------------------------------------------------------------
// ONE kernel, 384 blocks:
//  blocks 0..127 : prep(Mt,Tp0) | bar | Taylor-4 x3 | bar | powers d=1,2,4,8
//  blocks 128..383: gemm_u (u = bf16(x@B)), staging B from f32 on the fly
//  global rendezvous; blocks 0..63 phase1; 7 Kogge-Stone scan rounds
//  (blocks 64..79 square powers); all blocks carryexp; all blocks gemm_y.
__global__ __launch_bounds__(256, 2) void k_mega(
    const float* __restrict__ x, const float* __restrict__ A,
    const float* __restrict__ B, const float* __restrict__ C,
    const float* __restrict__ D, const float* __restrict__ h0,
    float* __restrict__ y,
    float* __restrict__ Mt, float* __restrict__ Tp0, float* __restrict__ Tp1,
    unsigned short* __restrict__ QSh, unsigned short* __restrict__ QSl,
    unsigned short* __restrict__ Et,
    unsigned short* __restrict__ Sh0, unsigned short* __restrict__ Sl0,
    unsigned short* __restrict__ Sh1, unsigned short* __restrict__ Sl1,
    float* __restrict__ g0, float* __restrict__ g1,
    unsigned short* __restrict__ u, unsigned short* __restrict__ hs,
    unsigned* ctrs){
  __shared__ unsigned short SM[2 * 128 * 40];   // 20480 B, re-purposed per stage
  int tid = threadIdx.x, lane = tid & 63, w = tid >> 6;
  int wr = w >> 1, wc = w & 1, l15 = lane & 15, quad = lane >> 4, q8 = quad * 8;
  int bid = blockIdx.x;
  const unsigned NB = 384;

  if (bid < 128) {
    // ======== prep: Mt = 0.1*A^T, Tp0 = I + Mt/4 ========
    {
      int base = bid * 512 + tid;
#pragma unroll
      for (int ii = 0; ii < 2; ++ii) {
        int i = base + ii * 256;
        int r = i >> 8, c = i & 255;
        float m = 0.1f * A[c * 256 + r];
        Mt[i] = m;
        Tp0[i] = m * 0.25f + (r == c ? 1.0f : 0.0f);
      }
    }
    gbar(&ctrs[0], 128);
    // ======== Taylor-4 (3 GEMM phases, 16 blocks active) ========
    unsigned short (*Bh)[40] = reinterpret_cast<unsigned short(*)[40]>(&SM[0]);
    unsigned short (*Bl)[40] = reinterpret_cast<unsigned short(*)[40]>(&SM[64 * 40]);
    const float alphas[3] = {1.0f / 3.0f, 0.5f, 1.0f};
#pragma unroll 1
    for (int ph = 0; ph < 3; ++ph) {
      const float* Bsrc = (ph == 1) ? Tp1 : Tp0;
      float* Odst = (ph == 0) ? Tp1 : Tp0;
      if (bid < 16) {
        int m0 = (bid >> 2) * 64, n0 = (bid & 3) * 64;
        f4v acc[2][2] = {};
        for (int kt = 0; kt < 256; kt += 32) {
          __syncthreads();
          {
            int col = tid & 63, kk0 = (tid >> 6) * 8;
#pragma unroll
            for (int j = 0; j < 8; ++j) {
              float v = Bsrc[(kt + kk0 + j) * 256 + n0 + col];
              unsigned short hi = f2bf(v);
              Bh[col][kk0 + j] = hi;
              Bl[col][kk0 + j] = f2bf(v - bf2f(hi));
            }
          }
          __syncthreads();
#pragma unroll
          for (int aq = 0; aq < 2; ++aq) {
            s8v ah, al;
            split8(&Mt[(m0 + wr * 32 + aq * 16 + l15) * 256 + kt + q8], ah, al);
#pragma unroll
            for (int bq = 0; bq < 2; ++bq) {
              s8v bh = *reinterpret_cast<const s8v*>(&Bh[wc * 32 + bq * 16 + l15][q8]);
              s8v bl = *reinterpret_cast<const s8v*>(&Bl[wc * 32 + bq * 16 + l15][q8]);
              acc[aq][bq] = __builtin_amdgcn_mfma_f32_16x16x32_bf16(ah, bh, acc[aq][bq], 0, 0, 0);
              acc[aq][bq] = __builtin_amdgcn_mfma_f32_16x16x32_bf16(ah, bl, acc[aq][bq], 0, 0, 0);
              acc[aq][bq] = __builtin_amdgcn_mfma_f32_16x16x32_bf16(al, bh, acc[aq][bq], 0, 0, 0);
            }
          }
        }
#pragma unroll
        for (int aq = 0; aq < 2; ++aq)
#pragma unroll
          for (int bq = 0; bq < 2; ++bq)
#pragma unroll
            for (int r = 0; r < 4; ++r) {
              int gm = m0 + wr * 32 + aq * 16 + quad * 4 + r;
              int gn = n0 + wc * 32 + bq * 16 + l15;
              float raw = alphas[ph] * acc[aq][bq][r];
              float v = raw + (gm == gn ? 1.0f : 0.0f);
              if (ph < 2) {
                Odst[gm * 256 + gn] = v;
              } else {
                unsigned short hi = f2bf(v);
                QSh[gm * 256 + gn] = hi;
                QSl[gm * 256 + gn] = f2bf(v - bf2f(hi));
                Et[gm * 256 + gn] = f2bf(raw);   // Q1 - I
              }
            }
      }
      gbar(&ctrs[1 + ph], 128);
    }
    // ======== power stack: QS[d+j] = QS[j] @ QS[d-1] ========
#pragma unroll 1
    for (int d = 1; d <= 8; d <<= 1) {
      int ntiles = d * 16;
      if (bid < ntiles) {
        int m0 = (bid >> 2) * 64, n0 = (bid & 3) * 64;
        int bro = (d - 1) * 256;
        f4v acc[2][2] = {};
        for (int kt = 0; kt < 256; kt += 32) {
          __syncthreads();
          {
            int col = tid & 63, kk0 = (tid >> 6) * 8;
#pragma unroll
            for (int j = 0; j < 8; ++j) {
              int k = kt + kk0 + j;
              Bh[col][kk0 + j] = QSh[(bro + k) * 256 + n0 + col];
              Bl[col][kk0 + j] = QSl[(bro + k) * 256 + n0 + col];
            }
          }
          __syncthreads();
#pragma unroll
          for (int aq = 0; aq < 2; ++aq) {
            s8v ah = *reinterpret_cast<const s8v*>(&QSh[(m0 + wr * 32 + aq * 16 + l15) * 256 + kt + q8]);
            s8v al = *reinterpret_cast<const s8v*>(&QSl[(m0 + wr * 32 + aq * 16 + l15) * 256 + kt + q8]);
#pragma unroll
            for (int bq = 0; bq < 2; ++bq) {
              s8v bh = *reinterpret_cast<const s8v*>(&Bh[wc * 32 + bq * 16 + l15][q8]);
              s8v bl = *reinterpret_cast<const s8v*>(&Bl[wc * 32 + bq * 16 + l15][q8]);
              acc[aq][bq] = __builtin_amdgcn_mfma_f32_16x16x32_bf16(ah, bh, acc[aq][bq], 0, 0, 0);
              acc[aq][bq] = __builtin_amdgcn_mfma_f32_16x16x32_bf16(ah, bl, acc[aq][bq], 0, 0, 0);
              acc[aq][bq] = __builtin_amdgcn_mfma_f32_16x16x32_bf16(al, bh, acc[aq][bq], 0, 0, 0);
            }
          }
        }
#pragma unroll
        for (int aq = 0; aq < 2; ++aq)
#pragma unroll
          for (int bq = 0; bq < 2; ++bq)
#pragma unroll
            for (int r = 0; r < 4; ++r) {
              int gm = m0 + wr * 32 + aq * 16 + quad * 4 + r;
              int gn = n0 + wc * 32 + bq * 16 + l15;
              float v = acc[aq][bq][r];
              unsigned short hi = f2bf(v);
              QSh[(d * 256 + gm) * 256 + gn] = hi;
              QSl[(d * 256 + gm) * 256 + gn] = f2bf(v - bf2f(hi));
            }
      }
      if (d < 8) gbar(&ctrs[4 + (d >> 1)], 128);   // sites 4,5,6 for d=1,2,4
    }
  } else {
    // ======== gemm_u: one 128x128 tile per block, K=1024 ========
    unsigned short (*Atile)[40] = reinterpret_cast<unsigned short(*)[40]>(&SM[0]);
    unsigned short (*Btile)[40] = reinterpret_cast<unsigned short(*)[40]>(&SM[128 * 40]);
    int ub = bid - 128;
    int m0 = (ub >> 1) * 128, n0 = (ub & 1) * 128;
    f4v acc[4][4] = {};
    for (int kt = 0; kt < 1024; kt += 32) {
      __syncthreads();
#pragma unroll
      for (int q = 0; q < 4; ++q) {
        int id = q * 256 + tid;
        int row = id >> 3, c4 = id & 7;
        float4 vv = *reinterpret_cast<const float4*>(&x[(m0 + row) * 1024 + kt + c4 * 4]);
        ushort4 hv;
        hv.x = f2bf(vv.x); hv.y = f2bf(vv.y); hv.z = f2bf(vv.z); hv.w = f2bf(vv.w);
        *reinterpret_cast<ushort4*>(&Atile[row][c4 * 4]) = hv;
      }
#pragma unroll
      for (int q = 0; q < 16; ++q) {
        int id = q * 256 + tid;
        int col = id & 127, kk = id >> 7;
        Btile[col][kk] = f2bf(B[(kt + kk) * 256 + n0 + col]);
      }
      __syncthreads();
      s8v af[4], bf[4];
#pragma unroll
      for (int aq = 0; aq < 4; ++aq)
        af[aq] = *reinterpret_cast<const s8v*>(&Atile[wr * 64 + aq * 16 + l15][q8]);
#pragma unroll
      for (int bq = 0; bq < 4; ++bq)
        bf[bq] = *reinterpret_cast<const s8v*>(&Btile[wc * 64 + bq * 16 + l15][q8]);
#pragma unroll
      for (int aq = 0; aq < 4; ++aq)
#pragma unroll
        for (int bq = 0; bq < 4; ++bq)
          acc[aq][bq] = __builtin_amdgcn_mfma_f32_16x16x32_bf16(af[aq], bf[bq], acc[aq][bq], 0, 0, 0);
    }
#pragma unroll
    for (int aq = 0; aq < 4; ++aq)
#pragma unroll
      for (int bq = 0; bq < 4; ++bq)
#pragma unroll
        for (int r = 0; r < 4; ++r) {
          int gm = m0 + wr * 64 + aq * 16 + quad * 4 + r;
          int gn = n0 + wc * 64 + bq * 16 + l15;
          u[gm * 256 + gn] = f2bf(acc[aq][bq][r]);
        }
  }

  gbar(&ctrs[7], NB);   // rendezvous: u, Et, QS all complete

  // ======== phase1: blocks 0..63, L=16 local scans ========
  if (bid < 64) {
    unsigned short (*hbuf)[16][264] = reinterpret_cast<unsigned short(*)[16][264]>(&SM[0]);
    int U0 = bid * 16;
    s8v e[4][8];
#pragma unroll
    for (int ct = 0; ct < 4; ++ct) {
      int col = w * 64 + ct * 16 + l15;
#pragma unroll
      for (int kt = 0; kt < 8; ++kt)
        e[ct][kt] = *reinterpret_cast<const s8v*>(&Et[col * 256 + kt * 32 + quad * 8]);
    }
    int rowbase[4];
#pragma unroll
    for (int r = 0; r < 4; ++r) {
      int g = U0 + quad * 4 + r;
      rowbase[r] = ((g >> 7) * 2048 + (g & 127) * 16) * 256;
    }
    for (int i = tid; i < 16 * 264; i += 256) hbuf[0][0][i] = 0;
    if (bid == 0)
      for (int i = tid; i < 2048; i += 256) g0[i] = h0[i];
    f4v acc[4] = {};
    float uv[4][4];
#pragma unroll
    for (int r = 0; r < 4; ++r)
#pragma unroll
      for (int ct = 0; ct < 4; ++ct)
        uv[r][ct] = bf2f(u[rowbase[r] + w * 64 + ct * 16 + l15]);
    __syncthreads();
    int cur = 0;
    for (int t = 0; t < 16; ++t) {
      s8v af[8];
#pragma unroll
      for (int kt = 0; kt < 8; ++kt)
        af[kt] = *reinterpret_cast<const s8v*>(&hbuf[cur][l15][kt * 32 + quad * 8]);
      float uvn[4][4];
      if (t < 15)
#pragma unroll
        for (int r = 0; r < 4; ++r)
#pragma unroll
          for (int ct = 0; ct < 4; ++ct)
            uvn[r][ct] = bf2f(u[rowbase[r] + (t + 1) * 256 + w * 64 + ct * 16 + l15]);
#pragma unroll
      for (int kt = 0; kt < 8; ++kt)
#pragma unroll
        for (int ct = 0; ct < 4; ++ct)
          acc[ct] = __builtin_amdgcn_mfma_f32_16x16x32_bf16(af[kt], e[ct][kt], acc[ct], 0, 0, 0);
      int nxt = cur ^ 1;
#pragma unroll
      for (int ct = 0; ct < 4; ++ct)
#pragma unroll
        for (int r = 0; r < 4; ++r) {
          acc[ct][r] += uv[r][ct];
          hbuf[nxt][quad * 4 + r][w * 64 + ct * 16 + l15] = f2bf(acc[ct][r]);
        }
      __syncthreads();
      int ul = w * 4 + quad, seg = l15;
      uint4 d0 = *reinterpret_cast<const uint4*>(&hbuf[nxt][ul][seg * 16]);
      uint4 d1 = *reinterpret_cast<const uint4*>(&hbuf[nxt][ul][seg * 16 + 8]);
      int g = U0 + ul;
      int hrow = ((g >> 7) * 2048 + (g & 127) * 16 + t) * 256;
      *reinterpret_cast<uint4*>(&hs[hrow + seg * 16]) = d0;
      *reinterpret_cast<uint4*>(&hs[hrow + seg * 16 + 8]) = d1;
      if (t < 15)
#pragma unroll
        for (int r = 0; r < 4; ++r)
#pragma unroll
          for (int ct = 0; ct < 4; ++ct)
            uv[r][ct] = uvn[r][ct];
      cur = nxt;
    }
#pragma unroll
    for (int ct = 0; ct < 4; ++ct)
#pragma unroll
      for (int r = 0; r < 4; ++r) {
        int g = U0 + quad * 4 + r;
        int k = g & 127, b = g >> 7;
        if (k < 127)
          g0[((k + 1) * 8 + b) * 256 + w * 64 + ct * 16 + l15] = acc[ct][r];
      }
  }

  gbar(&ctrs[8], NB);

  // ======== 7 Kogge-Stone scan rounds ========
  {
    unsigned short (*Bh)[40] = reinterpret_cast<unsigned short(*)[40]>(&SM[0]);
    unsigned short (*Bl)[40] = reinterpret_cast<unsigned short(*)[40]>(&SM[64 * 40]);
    const unsigned short* cSh = QSh + 15 * 65536;   // A16^T
    const unsigned short* cSl = QSl + 15 * 65536;
    float* gi = g0;
    float* go = g1;
#pragma unroll 1
    for (int rd = 0; rd < 7; ++rd) {
      int rs = 8 << rd;
      if (bid < 64) {
        int m0 = (bid >> 2) * 64, n0 = (bid & 3) * 64;
        f4v acc[2][2];
#pragma unroll
        for (int aq = 0; aq < 2; ++aq)
#pragma unroll
          for (int bq = 0; bq < 2; ++bq)
#pragma unroll
            for (int r = 0; r < 4; ++r)
              acc[aq][bq][r] = gi[(m0 + wr * 32 + aq * 16 + quad * 4 + r) * 256 +
                                  n0 + wc * 32 + bq * 16 + l15];
        for (int kt = 0; kt < 256; kt += 32) {
          s8v ah[2], al[2];
#pragma unroll
          for (int aq = 0; aq < 2; ++aq) {
            int ar = m0 + wr * 32 + aq * 16 + l15 - rs;
            if (ar >= 0) split8(&gi[ar * 256 + kt + q8], ah[aq], al[aq]);
            else { zero8(ah[aq]); zero8(al[aq]); }
          }
#pragma unroll
          for (int bq = 0; bq < 2; ++bq) {
            int bc = n0 + wc * 32 + bq * 16 + l15;
            s8v bh = *reinterpret_cast<const s8v*>(&cSh[bc * 256 + kt + q8]);
            s8v bl = *reinterpret_cast<const s8v*>(&cSl[bc * 256 + kt + q8]);
#pragma unroll
            for (int aq = 0; aq < 2; ++aq) {
              acc[aq][bq] = __builtin_amdgcn_mfma_f32_16x16x32_bf16(ah[aq], bh, acc[aq][bq], 0, 0, 0);
              acc[aq][bq] = __builtin_amdgcn_mfma_f32_16x16x32_bf16(ah[aq], bl, acc[aq][bq], 0, 0, 0);
              acc[aq][bq] = __builtin_amdgcn_mfma_f32_16x16x32_bf16(al[aq], bh, acc[aq][bq], 0, 0, 0);
            }
          }
        }
#pragma unroll
        for (int aq = 0; aq < 2; ++aq)
#pragma unroll
          for (int bq = 0; bq < 2; ++bq)
#pragma unroll
            for (int r = 0; r < 4; ++r)
              go[(m0 + wr * 32 + aq * 16 + quad * 4 + r) * 256 +
                 n0 + wc * 32 + bq * 16 + l15] = acc[aq][bq][r];
      } else if (bid < 80 && rd < 6) {
        // square the stride power for the next round
        unsigned short* dh = (rd & 1) ? Sh1 : Sh0;
        unsigned short* dl = (rd & 1) ? Sl1 : Sl0;
        int t = bid - 64;
        int m0 = (t >> 2) * 64, n0 = (t & 3) * 64;
        f4v acc[2][2] = {};
        for (int kt = 0; kt < 256; kt += 32) {
          __syncthreads();
          {
            int col = tid & 63, kk0 = (tid >> 6) * 8;
#pragma unroll
            for (int j = 0; j < 8; ++j) {
              int k = kt + kk0 + j;
              Bh[col][kk0 + j] = cSh[k * 256 + n0 + col];
              Bl[col][kk0 + j] = cSl[k * 256 + n0 + col];
            }
          }
          __syncthreads();
#pragma unroll
          for (int aq = 0; aq < 2; ++aq) {
            s8v ah = *reinterpret_cast<const s8v*>(&cSh[(m0 + wr * 32 + aq * 16 + l15) * 256 + kt + q8]);
            s8v al = *reinterpret_cast<const s8v*>(&cSl[(m0 + wr * 32 + aq * 16 + l15) * 256 + kt + q8]);
#pragma unroll
            for (int bq = 0; bq < 2; ++bq) {
              s8v bh = *reinterpret_cast<const s8v*>(&Bh[wc * 32 + bq * 16 + l15][q8]);
              s8v bl = *reinterpret_cast<const s8v*>(&Bl[wc * 32 + bq * 16 + l15][q8]);
              acc[aq][bq] = __builtin_amdgcn_mfma_f32_16x16x32_bf16(ah, bh, acc[aq][bq], 0, 0, 0);
              acc[aq][bq] = __builtin_amdgcn_mfma_f32_16x16x32_bf16(ah, bl, acc[aq][bq], 0, 0, 0);
              acc[aq][bq] = __builtin_amdgcn_mfma_f32_16x16x32_bf16(al, bh, acc[aq][bq], 0, 0, 0);
            }
          }
        }
#pragma unroll
        for (int aq = 0; aq < 2; ++aq)
#pragma unroll
          for (int bq = 0; bq < 2; ++bq)
#pragma unroll
            for (int r = 0; r < 4; ++r) {
              int gm = m0 + wr * 32 + aq * 16 + quad * 4 + r;
              int gn = n0 + wc * 32 + bq * 16 + l15;
              float v = acc[aq][bq][r];
              unsigned short hi = f2bf(v);
              dh[gm * 256 + gn] = hi;
              dl[gm * 256 + gn] = f2bf(v - bf2f(hi));
            }
      }
      gbar(&ctrs[9 + rd], NB);   // sites 9..15
      if (rd < 6) {
        cSh = (rd & 1) ? Sh1 : Sh0;
        cSl = (rd & 1) ? Sl1 : Sl0;
        float* tg = gi; gi = go; go = tg;
      }
    }
  }

  // ======== carry expansion: hs += carry @ [A_d^1..A_d^16] ========
  for (int t = bid; t < 1024; t += NB) {
    int m0 = (t >> 6) * 64, n0 = (t & 63) * 64;
    f4v acc[2][2] = {};
    for (int kt = 0; kt < 256; kt += 32) {
      s8v ah[2], al[2];
#pragma unroll
      for (int aq = 0; aq < 2; ++aq)
        split8(&g1[(m0 + wr * 32 + aq * 16 + l15) * 256 + kt + q8], ah[aq], al[aq]);
#pragma unroll
      for (int bq = 0; bq < 2; ++bq) {
        int bc = n0 + wc * 32 + bq * 16 + l15;
        s8v bh = *reinterpret_cast<const s8v*>(&QSh[bc * 256 + kt + q8]);
        s8v bl = *reinterpret_cast<const s8v*>(&QSl[bc * 256 + kt + q8]);
#pragma unroll
        for (int aq = 0; aq < 2; ++aq) {
          acc[aq][bq] = __builtin_amdgcn_mfma_f32_16x16x32_bf16(ah[aq], bh, acc[aq][bq], 0, 0, 0);
          acc[aq][bq] = __builtin_amdgcn_mfma_f32_16x16x32_bf16(ah[aq], bl, acc[aq][bq], 0, 0, 0);
          acc[aq][bq] = __builtin_amdgcn_mfma_f32_16x16x32_bf16(al[aq], bh, acc[aq][bq], 0, 0, 0);
        }
      }
    }
#pragma unroll
    for (int aq = 0; aq < 2; ++aq)
#pragma unroll
      for (int bq = 0; bq < 2; ++bq)
#pragma unroll
        for (int r = 0; r < 4; ++r) {
          int gm = m0 + wr * 32 + aq * 16 + quad * 4 + r;   // k*8+b
          int gn = n0 + wc * 32 + bq * 16 + l15;            // t0*256+n
          int k = gm >> 3, b = gm & 7, t0 = gn >> 8, nn = gn & 255;
          int idx = (b * 2048 + k * 16 + t0) * 256 + nn;
          hs[idx] = f2bf(bf2f(hs[idx]) + acc[aq][bq][r]);
        }
  }

  gbar(&ctrs[16], NB);

  // ======== gemm_y: y = hs @ C + x*D, 1024 tiles of 128x128 ========
  {
    unsigned short (*Atile)[40] = reinterpret_cast<unsigned short(*)[40]>(&SM[0]);
    unsigned short (*Btile)[40] = reinterpret_cast<unsigned short(*)[40]>(&SM[128 * 40]);
    for (int t = bid; t < 1024; t += NB) {
      int m0 = (t >> 3) * 128, n0 = (t & 7) * 128;
      f4v acc[4][4] = {};
      for (int kt = 0; kt < 256; kt += 32) {
        __syncthreads();
#pragma unroll
        for (int q = 0; q < 2; ++q) {
          int id = q * 256 + tid;
          int row = id >> 2, c8 = id & 3;
          uint4 av = *reinterpret_cast<const uint4*>(&hs[(m0 + row) * 256 + kt + c8 * 8]);
          *reinterpret_cast<uint4*>(&Atile[row][c8 * 8]) = av;
        }
#pragma unroll
        for (int q = 0; q < 16; ++q) {
          int id = q * 256 + tid;
          int col = id & 127, kk = id >> 7;
          Btile[col][kk] = f2bf(C[(kt + kk) * 1024 + n0 + col]);
        }
        __syncthreads();
        s8v af[4], bf[4];
#pragma unroll
        for (int aq = 0; aq < 4; ++aq)
          af[aq] = *reinterpret_cast<const s8v*>(&Atile[wr * 64 + aq * 16 + l15][q8]);
#pragma unroll
        for (int bq = 0; bq < 4; ++bq)
          bf[bq] = *reinterpret_cast<const s8v*>(&Btile[wc * 64 + bq * 16 + l15][q8]);
#pragma unroll
        for (int aq = 0; aq < 4; ++aq)
#pragma unroll
          for (int bq = 0; bq < 4; ++bq)
            acc[aq][bq] = __builtin_amdgcn_mfma_f32_16x16x32_bf16(af[aq], bf[bq], acc[aq][bq], 0, 0, 0);
      }
      __syncthreads();   // protect LDS before next tile iteration
#pragma unroll
      for (int bq = 0; bq < 4; ++bq) {
        int gn = n0 + wc * 64 + bq * 16 + l15;
        float dv = D[gn];
#pragma unroll
        for (int aq = 0; aq < 4; ++aq)
#pragma unroll
          for (int r = 0; r < 4; ++r) {
            int gm = m0 + wr * 64 + aq * 16 + quad * 4 + r;
            y[gm * 1024 + gn] = acc[aq][bq][r] + x[gm * 1024 + gn] * dv;
          }
      }
    }
  }
}

// ---------------------------------------------------------------------------
extern "C" void kernel_launch(void* const* d_in, const int* in_sizes, int n_in,
                              void* d_out, int out_size, void* d_ws, size_t ws_size,
                              hipStream_t stream) {
  (void)in_sizes; (void)n_in; (void)out_size; (void)ws_size;
  const float* x  = (const float*)d_in[0];
  const float* A  = (const float*)d_in[1];
  const float* B  = (const float*)d_in[2];
  const float* C  = (const float*)d_in[3];
  const float* D  = (const float*)d_in[4];
  const float* h0 = (const float*)d_in[5];
  float* y = (float*)d_out;

  char* ws = (char*)d_ws;
  size_t off = 0;
  auto alloc = [&](size_t bytes) { void* p = ws + off; off += (bytes + 255) & ~(size_t)255; return p; };
  float* Mt  = (float*)alloc(262144);
  float* Tp0 = (float*)alloc(262144);
  float* Tp1 = (float*)alloc(262144);
  unsigned short* QSh = (unsigned short*)alloc(2097152);
  unsigned short* QSl = (unsigned short*)alloc(2097152);
  unsigned short* Et  = (unsigned short*)alloc(131072);
  unsigned short* Sh0 = (unsigned short*)alloc(131072);
  unsigned short* Sl0 = (unsigned short*)alloc(131072);
  unsigned short* Sh1 = (unsigned short*)alloc(131072);
  unsigned short* Sl1 = (unsigned short*)alloc(131072);
  float* g0 = (float*)alloc(1048576);
  float* g1 = (float*)alloc(1048576);
  unsigned short* u  = (unsigned short*)alloc(8388608);
  unsigned short* hs = (unsigned short*)alloc(8388608);
  unsigned* ctrs = (unsigned*)alloc(256);

  hipMemsetAsync(ctrs, 0, 256, stream);
  k_mega<<<384, 256, 0, stream>>>(x, A, B, C, D, h0, y,
                                  Mt, Tp0, Tp1, QSh, QSl, Et,
                                  Sh0, Sl0, Sh1, Sl1, g0, g1, u, hs, ctrs);
}